// Round 4
// baseline (2925.932 us; speedup 1.0000x reference)
//
#include <hip/hip_runtime.h>
#include <hip/hip_bf16.h>
#include <math.h>

#define B_    32
#define HH    56
#define WW_   56
#define C_    192
#define WS_   7
#define SHIFT_ 3
#define HEADS_ 6
#define DH    32
#define N_    49
#define NW_   64
#define NWIN  2048
#define ROWS  100352
#define HID_  768
#define QKVN  576
#define NPAD  52          // N_ padded to multiple of 4 for float4 LDS reads

// attn_mask flat element 16812 is -100.0 (window 7, n=0, m=5).
// bf16 buffer: u16[16812] = 0xC2C8.  f32 buffer: u16[16812] = low half of
// element 8406 = 0x0000 (both 0.0f and -100.0f have zero low mantissa halves).
#define DET_IDX 16812

typedef __hip_bfloat16 bf16;

__device__ __forceinline__ float b2f(bf16 v){ return __bfloat162float(v); }
__device__ __forceinline__ bf16  f2b(float v){ return __float2bfloat16(v); }

template<bool BF>
__device__ __forceinline__ float ldf(const void* p, size_t i){
  if (BF) return b2f(((const bf16*)p)[i]);
  return ((const float*)p)[i];
}
template<bool BF>
__device__ __forceinline__ void stf(void* p, size_t i, float v){
  if (BF) ((bf16*)p)[i] = f2b(v);
  else    ((float*)p)[i] = v;
}
__device__ __forceinline__ bool detect_bf16(const void* mask){
  return ((const unsigned short*)mask)[DET_IDX] != 0;
}

// ---------------- shared-memory layouts (declared in __global__, passed down) ----------------
struct __align__(16) AttnSmem {
  float hsT[C_ * NPAD];          // [c][n] LN'd window, later attn-out transposed  39.9 KB
  bf16  qkvs[3*HEADS_*N_*DH];    // [which][head][n][d]                            56.4 KB
  float S[N_][N_+1];             //                                                 9.8 KB
  float mus[N_], rss[N_];
  int   srows[N_];
};
struct __align__(16) MlpSmem {
  float ts[8][C_];
  float hid[8][HID_];
  float part[4][8][C_];
  float mus[8], rss[8];
};

// ================= Kernel 1 body: LN1 + shift + attention + proj + residual =================
template<bool BF>
__device__ void attn_body(AttnSmem& sm,
    const void* __restrict__ x,
    const void* __restrict__ n1w, const void* __restrict__ n1b,
    const void* __restrict__ qkvw, const void* __restrict__ qkvb,
    const void* __restrict__ btab, const int* __restrict__ rel,
    const void* __restrict__ mask,
    const void* __restrict__ projw, const void* __restrict__ projb,
    void* __restrict__ out)
{
  int win  = blockIdx.x;
  int tid  = threadIdx.x;
  int lane = tid & 63, wave = tid >> 6;

  if (tid < N_) {
    int bb = win >> 6, wi = win & 63;
    int wh = wi >> 3, ww = wi & 7;
    int th = tid / WS_, tw = tid % WS_;
    int sh = wh*WS_ + th + SHIFT_; if (sh >= HH) sh -= HH;
    int sw = ww*WS_ + tw + SHIFT_; if (sw >= WW_) sw -= WW_;
    sm.srows[tid] = bb*HH*WW_ + sh*WW_ + sw;
  }
  for (int idx = tid; idx < C_*3; idx += 256)
    sm.hsT[(idx/3)*NPAD + N_ + (idx%3)] = 0.f;
  __syncthreads();

  // --- phase A: gather + LN1 ---
  for (int idx = tid; idx < N_*C_; idx += 256) {
    int n = idx / C_, c = idx % C_;
    sm.hsT[c*NPAD + n] = ldf<BF>(x, (size_t)sm.srows[n]*C_ + c);
  }
  __syncthreads();
  for (int r = wave; r < N_; r += 4) {
    float v0 = sm.hsT[lane*NPAD + r];
    float v1 = sm.hsT[(lane+64)*NPAD + r];
    float v2 = sm.hsT[(lane+128)*NPAD + r];
    float s = v0+v1+v2, q = v0*v0+v1*v1+v2*v2;
    #pragma unroll
    for (int m = 32; m; m >>= 1) { s += __shfl_xor(s, m); q += __shfl_xor(q, m); }
    if (lane == 0) {
      float mu = s*(1.f/C_), var = q*(1.f/C_) - mu*mu;
      sm.mus[r] = mu; sm.rss[r] = rsqrtf(var + 1e-5f);
    }
  }
  __syncthreads();
  for (int idx = tid; idx < C_*N_; idx += 256) {
    int c = idx / N_, n = idx % N_;
    sm.hsT[c*NPAD + n] = (sm.hsT[c*NPAD + n] - sm.mus[n])*sm.rss[n]*ldf<BF>(n1w,c) + ldf<BF>(n1b,c);
  }
  __syncthreads();

  // --- phase B: qkv projection into LDS ---
  for (int jj = 0; jj < QKVN; jj += 256) {
    int jc = jj + tid;
    if (jc < QKVN) {
      float acc[NPAD];
      #pragma unroll
      for (int n = 0; n < NPAD; n++) acc[n] = 0.f;
      for (int c = 0; c < C_; c++) {
        float wv = ldf<BF>(qkvw, (size_t)c*QKVN + jc);
        const float4* hp = (const float4*)&sm.hsT[c*NPAD];
        #pragma unroll
        for (int g = 0; g < 13; g++) {
          float4 h4 = hp[g];
          acc[4*g+0] += h4.x*wv; acc[4*g+1] += h4.y*wv;
          acc[4*g+2] += h4.z*wv; acc[4*g+3] += h4.w*wv;
        }
      }
      float bv = ldf<BF>(qkvb, jc);
      int which = jc / C_;
      int cc = jc % C_;
      int head = cc >> 5, d = cc & 31;
      float sc = (which == 0) ? 0.17677669529663689f : 1.f;
      int base = (which*HEADS_ + head)*N_*DH + d;
      #pragma unroll
      for (int n = 0; n < N_; n++)
        sm.qkvs[base + n*DH] = f2b((acc[n] + bv)*sc);
    }
  }
  __syncthreads();

  // --- phase C: per-head attention ---
  int wi = win & 63;
  for (int head = 0; head < HEADS_; head++) {
    const bf16* qh = &sm.qkvs[(0*HEADS_ + head)*N_*DH];
    const bf16* kh = &sm.qkvs[(1*HEADS_ + head)*N_*DH];
    const bf16* vh = &sm.qkvs[(2*HEADS_ + head)*N_*DH];
    for (int e = tid; e < N_*N_; e += 256) {
      int n = e / N_, m = e % N_;
      float a = 0.f;
      #pragma unroll
      for (int d = 0; d < DH; d++) a += b2f(qh[n*DH+d])*b2f(kh[m*DH+d]);
      a += ldf<BF>(btab, (size_t)rel[e]*HEADS_ + head);
      a += ldf<BF>(mask, (size_t)wi*N_*N_ + e);
      sm.S[n][m] = a;
    }
    __syncthreads();
    if (tid < N_) {
      float mx = -1e30f;
      for (int m = 0; m < N_; m++) mx = fmaxf(mx, sm.S[tid][m]);
      float sum = 0.f;
      for (int m = 0; m < N_; m++) { float e2 = __expf(sm.S[tid][m]-mx); sm.S[tid][m] = e2; sum += e2; }
      float inv = 1.f/sum;
      for (int m = 0; m < N_; m++) sm.S[tid][m] *= inv;
    }
    __syncthreads();
    for (int e = tid; e < N_*DH; e += 256) {
      int n = e >> 5, d = e & 31;
      float a = 0.f;
      #pragma unroll
      for (int m = 0; m < N_; m++) a += sm.S[n][m]*b2f(vh[m*DH+d]);
      sm.hsT[(head*DH + d)*NPAD + n] = a;
    }
    __syncthreads();
  }

  // --- phase D: proj + residual, inverse scatter ---
  if (tid < C_) {
    int c = tid;
    float acc[NPAD];
    #pragma unroll
    for (int n = 0; n < NPAD; n++) acc[n] = 0.f;
    for (int k = 0; k < C_; k++) {
      float wv = ldf<BF>(projw, (size_t)k*C_ + c);
      const float4* hp = (const float4*)&sm.hsT[k*NPAD];
      #pragma unroll
      for (int g = 0; g < 13; g++) {
        float4 h4 = hp[g];
        acc[4*g+0] += h4.x*wv; acc[4*g+1] += h4.y*wv;
        acc[4*g+2] += h4.z*wv; acc[4*g+3] += h4.w*wv;
      }
    }
    float pb = ldf<BF>(projb, c);
    #pragma unroll
    for (int n = 0; n < N_; n++) {
      size_t gr = (size_t)sm.srows[n]*C_ + c;
      stf<BF>(out, gr, ldf<BF>(x, gr) + acc[n] + pb);
    }
  }
}

__global__ __launch_bounds__(256) void k_attn_fused(
    const void* x, const void* n1w, const void* n1b,
    const void* qkvw, const void* qkvb,
    const void* btab, const int* rel, const void* mask,
    const void* projw, const void* projb, void* out)
{
  __shared__ AttnSmem sm;
  if (detect_bf16(mask))
    attn_body<true >(sm, x, n1w, n1b, qkvw, qkvb, btab, rel, mask, projw, projb, out);
  else
    attn_body<false>(sm, x, n1w, n1b, qkvw, qkvb, btab, rel, mask, projw, projb, out);
}

// ================= Kernel 2 body: LN2 + fc1 + GELU + fc2 + residual (in-place) =================
template<bool BF>
__device__ void mlp_body(MlpSmem& sm, void* __restrict__ y,
    const void* __restrict__ n2w, const void* __restrict__ n2b,
    const void* __restrict__ w1, const void* __restrict__ b1,
    const void* __restrict__ w2, const void* __restrict__ b2)
{
  int r0 = blockIdx.x * 8;
  int tid = threadIdx.x, lane = tid & 63, wave = tid >> 6;

  for (int idx = tid; idx < 8*C_; idx += 256)
    sm.ts[idx/C_][idx%C_] = ldf<BF>(y, (size_t)r0*C_ + idx);
  __syncthreads();
  for (int r = wave; r < 8; r += 4) {
    float v0 = sm.ts[r][lane], v1 = sm.ts[r][lane+64], v2 = sm.ts[r][lane+128];
    float s = v0+v1+v2, q = v0*v0+v1*v1+v2*v2;
    #pragma unroll
    for (int m = 32; m; m >>= 1) { s += __shfl_xor(s, m); q += __shfl_xor(q, m); }
    if (lane == 0) {
      float mu = s*(1.f/C_), var = q*(1.f/C_) - mu*mu;
      sm.mus[r] = mu; sm.rss[r] = rsqrtf(var + 1e-5f);
    }
  }
  __syncthreads();
  for (int idx = tid; idx < 8*C_; idx += 256) {
    int r = idx / C_, c = idx % C_;
    sm.ts[r][c] = (sm.ts[r][c] - sm.mus[r])*sm.rss[r]*ldf<BF>(n2w,c) + ldf<BF>(n2b,c);
  }
  __syncthreads();

  // fc1 + exact GELU
  {
    float a0[8], a1[8], a2[8];
    #pragma unroll
    for (int r = 0; r < 8; r++) { a0[r]=0.f; a1[r]=0.f; a2[r]=0.f; }
    for (int kk = 0; kk < C_; kk++) {
      float w0 = ldf<BF>(w1, (size_t)kk*HID_ + tid);
      float wA = ldf<BF>(w1, (size_t)kk*HID_ + tid + 256);
      float wB = ldf<BF>(w1, (size_t)kk*HID_ + tid + 512);
      #pragma unroll
      for (int r = 0; r < 8; r++) {
        float tv = sm.ts[r][kk];
        a0[r] += tv*w0; a1[r] += tv*wA; a2[r] += tv*wB;
      }
    }
    float bb0 = ldf<BF>(b1, tid), bbA = ldf<BF>(b1, tid+256), bbB = ldf<BF>(b1, tid+512);
    #pragma unroll
    for (int r = 0; r < 8; r++) {
      float g0 = a0[r] + bb0, gA = a1[r] + bbA, gB = a2[r] + bbB;
      sm.hid[r][tid]     = 0.5f*g0*(1.f + erff(g0*0.70710678118654752f));
      sm.hid[r][tid+256] = 0.5f*gA*(1.f + erff(gA*0.70710678118654752f));
      sm.hid[r][tid+512] = 0.5f*gB*(1.f + erff(gB*0.70710678118654752f));
    }
  }
  __syncthreads();

  // fc2 split across 4 waves + LDS reduce
  {
    float a0[8], a1[8], a2[8];
    #pragma unroll
    for (int r = 0; r < 8; r++) { a0[r]=0.f; a1[r]=0.f; a2[r]=0.f; }
    int h0 = wave*192;
    for (int hh = 0; hh < 192; hh++) {
      int h = h0 + hh;
      float w0 = ldf<BF>(w2, (size_t)h*C_ + lane);
      float wA = ldf<BF>(w2, (size_t)h*C_ + lane + 64);
      float wB = ldf<BF>(w2, (size_t)h*C_ + lane + 128);
      #pragma unroll
      for (int r = 0; r < 8; r++) {
        float hv = sm.hid[r][h];
        a0[r] += hv*w0; a1[r] += hv*wA; a2[r] += hv*wB;
      }
    }
    #pragma unroll
    for (int r = 0; r < 8; r++) {
      sm.part[wave][r][lane]      = a0[r];
      sm.part[wave][r][lane+64]   = a1[r];
      sm.part[wave][r][lane+128]  = a2[r];
    }
  }
  __syncthreads();
  for (int idx = tid; idx < 8*C_; idx += 256) {
    int r = idx / C_, c = idx % C_;
    float s = sm.part[0][r][c] + sm.part[1][r][c] + sm.part[2][r][c] + sm.part[3][r][c];
    size_t gr = (size_t)(r0 + r)*C_ + c;
    stf<BF>(y, gr, ldf<BF>(y, gr) + s + ldf<BF>(b2, c));
  }
}

__global__ __launch_bounds__(256) void k_mlp(
    void* y, const void* n2w, const void* n2b,
    const void* w1, const void* b1, const void* w2, const void* b2,
    const void* mask /* detection only */)
{
  __shared__ MlpSmem sm;
  if (detect_bf16(mask))
    mlp_body<true >(sm, y, n2w, n2b, w1, b1, w2, b2);
  else
    mlp_body<false>(sm, y, n2w, n2b, w1, b1, w2, b2);
}

extern "C" void kernel_launch(void* const* d_in, const int* in_sizes, int n_in,
                              void* d_out, int out_size, void* d_ws, size_t ws_size,
                              hipStream_t stream) {
  const void* x     = d_in[0];
  const void* n1w   = d_in[1];
  const void* n1b   = d_in[2];
  const void* qkvw  = d_in[3];
  const void* qkvb  = d_in[4];
  const void* btab  = d_in[5];
  const void* projw = d_in[6];
  const void* projb = d_in[7];
  const void* n2w   = d_in[8];
  const void* n2b   = d_in[9];
  const void* w1    = d_in[10];
  const void* b1    = d_in[11];
  const void* w2    = d_in[12];
  const void* b2    = d_in[13];
  const void* mask  = d_in[14];
  const int*  rel   = (const int*)d_in[15];

  (void)d_ws; (void)ws_size; (void)in_sizes; (void)n_in; (void)out_size;

  k_attn_fused<<<NWIN, 256, 0, stream>>>(x, n1w, n1b, qkvw, qkvb, btab, rel, mask,
                                         projw, projb, d_out);
  k_mlp<<<ROWS/8, 256, 0, stream>>>(d_out, n2w, n2b, w1, b1, w2, b2, mask);
}

// Round 6
// 902.205 us; speedup vs baseline: 3.2431x; 3.2431x over previous
//
#include <hip/hip_runtime.h>
#include <math.h>

#define B_    32
#define HH    56
#define WW_   56
#define C_    192
#define WS_   7
#define SHIFT_ 3
#define HEADS_ 6
#define DH    32
#define N_    49
#define NWIN  2048
#define ROWS  100352
#define HID_  768
#define QKVN  576

typedef __bf16 bfr;
typedef __bf16 bf8 __attribute__((ext_vector_type(8)));
typedef float  f32x4 __attribute__((ext_vector_type(4)));

#define MFMA16(a,b,c) __builtin_amdgcn_mfma_f32_16x16x32_bf16(a,b,c,0,0,0)

// ---- ws layout (bf16 elements): transposed weights [N][K] for B-fragments ----
#define OQW   0         // qkvwT [576][192]
#define OPW   110592    // projwT[192][192]
#define OW1   147456    // w1T   [768][192]
#define OW2   294912    // w2T   [192][768]
#define WTOT  442368    // *2 B = 884,736 bytes of d_ws

// ================= k_prep: transpose + fp32->bf16 all weights into ws =================
__global__ __launch_bounds__(256) void k_prep(
    const float* __restrict__ qkvw, const float* __restrict__ projw,
    const float* __restrict__ w1,   const float* __restrict__ w2,
    bfr* __restrict__ wsp)
{
  int idx = blockIdx.x*256 + threadIdx.x;
  if (idx >= WTOT) return;
  if (idx < OPW)      { int i=idx;      int n=i/192, k=i%192; wsp[idx] = (bfr)qkvw[k*QKVN + n]; }
  else if (idx < OW1) { int i=idx-OPW;  int n=i/192, k=i%192; wsp[idx] = (bfr)projw[k*C_ + n]; }
  else if (idx < OW2) { int i=idx-OW1;  int n=i/192, k=i%192; wsp[idx] = (bfr)w1[k*HID_ + n]; }
  else                { int i=idx-OW2;  int n=i/768, k=i%768; wsp[idx] = (bfr)w2[k*C_ + n]; }
}

// ================= Kernel 1: LN1 + shift + QKV + attention + proj + residual =================
// LDS layout (bytes):
#define SM_HS 0         // bfr hs[64][200]  (h after LN; reused as attn-out "os")  25600
#define SM_Q  25600     // bfr qs[6][64][32]                                        24576
#define SM_K  50176     // bfr ks[6][64][32]                                        24576
#define SM_V  74752     // bfr vT[6][32][72]                                        27648
#define SM_S  102400    // float S[64][66]                                          16896
#define SM_P  119296    // bfr P[64][72]                                             9216
#define SM_SR 128512    // int srows[64]                                              256
#define SM1_TOT 128768
#define HSP 200

__global__ __launch_bounds__(256) void k_attn(
    const float* __restrict__ x,
    const float* __restrict__ n1w, const float* __restrict__ n1b,
    const bfr*   __restrict__ wsp,
    const float* __restrict__ qkvb,
    const float* __restrict__ btab, const int* __restrict__ rel,
    const float* __restrict__ mask,
    const float* __restrict__ projb,
    float* __restrict__ out)
{
  __shared__ char smem[SM1_TOT];
  bfr*   hs    = (bfr*)(smem + SM_HS);
  bfr*   qs    = (bfr*)(smem + SM_Q);
  bfr*   ks    = (bfr*)(smem + SM_K);
  bfr*   vT    = (bfr*)(smem + SM_V);
  float* S     = (float*)(smem + SM_S);
  bfr*   P     = (bfr*)(smem + SM_P);
  int*   srows = (int*)(smem + SM_SR);
  float* pj    = (float*)(smem + SM_Q);   // overlay: proj staging fp32 [64][196] (50176 B <= 76800)

  const f32x4 ZERO4 = {0.f, 0.f, 0.f, 0.f};

  int win  = blockIdx.x;
  int tid  = threadIdx.x;
  int lane = tid & 63, wave = tid >> 6;
  int ln15 = lane & 15, quad = lane >> 4;
  int wi   = win & 63;

  // ---- phase A: srows, zero hs, gather + LN1 ----
  if (tid < N_) {
    int bb = win >> 6;
    int wh = wi >> 3, ww = wi & 7;
    int th = tid / WS_, tw = tid % WS_;
    int sh = wh*WS_ + th + SHIFT_; if (sh >= HH) sh -= HH;
    int sw = ww*WS_ + tw + SHIFT_; if (sw >= WW_) sw -= WW_;
    srows[tid] = bb*HH*WW_ + sh*WW_ + sw;
  }
  {
    int* hz = (int*)hs;
    for (int i = tid; i < 64*HSP/2; i += 256) hz[i] = 0;
  }
  __syncthreads();
  for (int r = wave; r < N_; r += 4) {
    const float* xr = x + (size_t)srows[r]*C_;
    float v0 = xr[lane], v1 = xr[lane+64], v2 = xr[lane+128];
    float s = v0+v1+v2, q = v0*v0+v1*v1+v2*v2;
    #pragma unroll
    for (int m = 32; m; m >>= 1) { s += __shfl_xor(s, m); q += __shfl_xor(q, m); }
    float mu = s*(1.f/C_), var = q*(1.f/C_) - mu*mu;
    float rs = rsqrtf(var + 1e-5f);
    hs[r*HSP + lane]     = (bfr)((v0-mu)*rs*n1w[lane]     + n1b[lane]);
    hs[r*HSP + lane+64]  = (bfr)((v1-mu)*rs*n1w[lane+64]  + n1b[lane+64]);
    hs[r*HSP + lane+128] = (bfr)((v2-mu)*rs*n1w[lane+128] + n1b[lane+128]);
  }
  __syncthreads();

  // ---- phase B: QKV GEMM (M=64, N=576, K=192) via MFMA ----
  {
    const bfr* qkvwT = wsp + OQW;
    for (int ch = 0; ch < 3; ch++) {
      int ntBase = wave*9 + ch*3;
      f32x4 acc[3][4];
      #pragma unroll
      for (int j=0;j<3;j++)
        #pragma unroll
        for (int mt=0;mt<4;mt++) acc[j][mt] = ZERO4;
      for (int k0 = 0; k0 < C_; k0 += 32) {
        bf8 afr[4];
        #pragma unroll
        for (int mt=0;mt<4;mt++)
          afr[mt] = *(const bf8*)&hs[(mt*16+ln15)*HSP + k0 + quad*8];
        #pragma unroll
        for (int j=0;j<3;j++) {
          int nt = ntBase + j;
          bf8 bw = *(const bf8*)&qkvwT[(size_t)(nt*16+ln15)*192 + k0 + quad*8];
          #pragma unroll
          for (int mt=0;mt<4;mt++) acc[j][mt] = MFMA16(afr[mt], bw, acc[j][mt]);
        }
      }
      #pragma unroll
      for (int j=0;j<3;j++) {
        int jc = (ntBase+j)*16 + ln15;
        float bias = qkvb[jc];
        int which = jc/192, cc = jc%192;
        int head = cc >> 5, d = cc & 31;
        #pragma unroll
        for (int mt=0;mt<4;mt++)
          #pragma unroll
          for (int r=0;r<4;r++) {
            int row = mt*16 + quad*4 + r;
            float val = acc[j][mt][r] + bias;
            if (which == 0)      qs[(head*64+row)*DH + d] = (bfr)(val*0.17677669529663689f);
            else if (which == 1) ks[(head*64+row)*DH + d] = (bfr)val;
            else                 vT[(head*DH+d)*72 + row] = (bfr)val;
          }
      }
    }
  }
  __syncthreads();

  // ---- phase C: attention per head (QK^T -> softmax -> PV) ----
  for (int head = 0; head < HEADS_; head++) {
    // QK^T: 16 tiles (4 Mt x 4 Nt), K=32 (one MFMA)
    #pragma unroll
    for (int i = 0; i < 4; i++) {
      int tt = wave*4 + i, mt = tt >> 2, nt = tt & 3;
      bf8 aq = *(const bf8*)&qs[(head*64 + mt*16+ln15)*DH + quad*8];
      bf8 bk = *(const bf8*)&ks[(head*64 + nt*16+ln15)*DH + quad*8];
      f32x4 c = MFMA16(aq, bk, ZERO4);
      int mcol = nt*16 + ln15;
      #pragma unroll
      for (int r=0;r<4;r++) {
        int nrow = mt*16 + quad*4 + r;
        float sv;
        if (nrow < N_ && mcol < N_) {
          int e = nrow*N_ + mcol;
          sv = c[r] + btab[rel[e]*HEADS_ + head] + mask[(size_t)wi*N_*N_ + e];
        } else sv = -1e30f;
        S[nrow*66 + mcol] = sv;
      }
    }
    __syncthreads();
    // softmax: one thread per row (64 rows)
    if (tid < 64) {
      float mx = -1e30f;
      for (int m = 0; m < 64; m++) mx = fmaxf(mx, S[tid*66+m]);
      float sum = 0.f;
      for (int m = 0; m < 64; m++) { float e2 = __expf(S[tid*66+m]-mx); S[tid*66+m] = e2; sum += e2; }
      float inv = 1.f/sum;
      for (int m = 0; m < 64; m++) P[tid*72+m] = (bfr)(S[tid*66+m]*inv);
    }
    __syncthreads();
    // PV: 8 tiles (4 Mt x 2 Nt), K=64 (two MFMA)
    #pragma unroll
    for (int i = 0; i < 2; i++) {
      int tt = wave*2 + i, mt = tt >> 1, nt = tt & 1;
      f32x4 c = ZERO4;
      #pragma unroll
      for (int k0 = 0; k0 < 64; k0 += 32) {
        bf8 ap = *(const bf8*)&P[(mt*16+ln15)*72 + k0 + quad*8];
        bf8 bv = *(const bf8*)&vT[(head*DH + nt*16+ln15)*72 + k0 + quad*8];
        c = MFMA16(ap, bv, c);
      }
      int d = nt*16 + ln15;
      #pragma unroll
      for (int r=0;r<4;r++) {
        int row = mt*16 + quad*4 + r;
        hs[row*HSP + head*DH + d] = (bfr)c[r];   // os
      }
    }
    __syncthreads();
  }

  // ---- phase D: proj (M=64, N=192, K=192) + bias -> pj staging ----
  {
    const bfr* projwT = wsp + OPW;
    int ntBase = wave*3;
    f32x4 acc[3][4];
    #pragma unroll
    for (int j=0;j<3;j++)
      #pragma unroll
      for (int mt=0;mt<4;mt++) acc[j][mt] = ZERO4;
    for (int k0 = 0; k0 < C_; k0 += 32) {
      bf8 afr[4];
      #pragma unroll
      for (int mt=0;mt<4;mt++)
        afr[mt] = *(const bf8*)&hs[(mt*16+ln15)*HSP + k0 + quad*8];
      #pragma unroll
      for (int j=0;j<3;j++) {
        int nt = ntBase + j;
        bf8 bw = *(const bf8*)&projwT[(size_t)(nt*16+ln15)*192 + k0 + quad*8];
        #pragma unroll
        for (int mt=0;mt<4;mt++) acc[j][mt] = MFMA16(afr[mt], bw, acc[j][mt]);
      }
    }
    #pragma unroll
    for (int j=0;j<3;j++) {
      int col = (ntBase+j)*16 + ln15;
      float pb = projb[col];
      #pragma unroll
      for (int mt=0;mt<4;mt++)
        #pragma unroll
        for (int r=0;r<4;r++) {
          int row = mt*16 + quad*4 + r;
          pj[row*196 + col] = acc[j][mt][r] + pb;
        }
    }
  }
  __syncthreads();
  // final: residual + inverse scatter, coalesced
  for (int idx = tid; idx < N_*C_; idx += 256) {
    int n = idx / C_, c = idx % C_;
    size_t gr = (size_t)srows[n]*C_ + c;
    out[gr] = x[gr] + pj[n*196 + c];
  }
}

// ================= Kernel 2: LN2 + fc1 + GELU + fc2 + residual (in-place on d_out) =================
#define SM2_TS  0        // bfr ts[64][200]   25600
#define SM2_HID 25600    // bfr hid[64][776]  99328 ; overlay: float st[64][196] 50176
#define SM2_TOT 124928

__global__ __launch_bounds__(256) void k_mlp(
    float* __restrict__ y,
    const float* __restrict__ n2w, const float* __restrict__ n2b,
    const bfr* __restrict__ wsp,
    const float* __restrict__ b1, const float* __restrict__ b2)
{
  __shared__ char smem[SM2_TOT];
  bfr*   ts  = (bfr*)(smem + SM2_TS);
  bfr*   hid = (bfr*)(smem + SM2_HID);
  float* st  = (float*)(smem + SM2_HID);

  const f32x4 ZERO4 = {0.f, 0.f, 0.f, 0.f};

  int r0 = blockIdx.x * 64;
  int tid = threadIdx.x;
  int lane = tid & 63, wave = tid >> 6;
  int ln15 = lane & 15, quad = lane >> 4;

  // ---- LN2 ----
  for (int r = wave; r < 64; r += 4) {
    const float* yr = y + (size_t)(r0 + r)*C_;
    float v0 = yr[lane], v1 = yr[lane+64], v2 = yr[lane+128];
    float s = v0+v1+v2, q = v0*v0+v1*v1+v2*v2;
    #pragma unroll
    for (int m = 32; m; m >>= 1) { s += __shfl_xor(s, m); q += __shfl_xor(q, m); }
    float mu = s*(1.f/C_), var = q*(1.f/C_) - mu*mu;
    float rs = rsqrtf(var + 1e-5f);
    ts[r*HSP + lane]     = (bfr)((v0-mu)*rs*n2w[lane]     + n2b[lane]);
    ts[r*HSP + lane+64]  = (bfr)((v1-mu)*rs*n2w[lane+64]  + n2b[lane+64]);
    ts[r*HSP + lane+128] = (bfr)((v2-mu)*rs*n2w[lane+128] + n2b[lane+128]);
  }
  __syncthreads();

  // ---- fc1 + exact GELU (M=64, N=768, K=192) ----
  {
    const bfr* w1T = wsp + OW1;
    for (int ch = 0; ch < 4; ch++) {
      int ntBase = wave*12 + ch*3;
      f32x4 acc[3][4];
      #pragma unroll
      for (int j=0;j<3;j++)
        #pragma unroll
        for (int mt=0;mt<4;mt++) acc[j][mt] = ZERO4;
      for (int k0 = 0; k0 < C_; k0 += 32) {
        bf8 afr[4];
        #pragma unroll
        for (int mt=0;mt<4;mt++)
          afr[mt] = *(const bf8*)&ts[(mt*16+ln15)*HSP + k0 + quad*8];
        #pragma unroll
        for (int j=0;j<3;j++) {
          int nt = ntBase + j;
          bf8 bw = *(const bf8*)&w1T[(size_t)(nt*16+ln15)*192 + k0 + quad*8];
          #pragma unroll
          for (int mt=0;mt<4;mt++) acc[j][mt] = MFMA16(afr[mt], bw, acc[j][mt]);
        }
      }
      #pragma unroll
      for (int j=0;j<3;j++) {
        int col = (ntBase+j)*16 + ln15;
        float bb = b1[col];
        #pragma unroll
        for (int mt=0;mt<4;mt++)
          #pragma unroll
          for (int r=0;r<4;r++) {
            int row = mt*16 + quad*4 + r;
            float g = acc[j][mt][r] + bb;
            hid[row*776 + col] = (bfr)(0.5f*g*(1.f + erff(g*0.70710678118654752f)));
          }
      }
    }
  }
  __syncthreads();

  // ---- fc2 (M=64, N=192, K=768) ----
  {
    const bfr* w2T = wsp + OW2;
    int ntBase = wave*3;
    f32x4 acc[3][4];
    #pragma unroll
    for (int j=0;j<3;j++)
      #pragma unroll
      for (int mt=0;mt<4;mt++) acc[j][mt] = ZERO4;
    for (int k0 = 0; k0 < HID_; k0 += 32) {
      bf8 afr[4];
      #pragma unroll
      for (int mt=0;mt<4;mt++)
        afr[mt] = *(const bf8*)&hid[(mt*16+ln15)*776 + k0 + quad*8];
      #pragma unroll
      for (int j=0;j<3;j++) {
        int nt = ntBase + j;
        bf8 bw = *(const bf8*)&w2T[(size_t)(nt*16+ln15)*768 + k0 + quad*8];
        #pragma unroll
        for (int mt=0;mt<4;mt++) acc[j][mt] = MFMA16(afr[mt], bw, acc[j][mt]);
      }
    }
    __syncthreads();   // all waves done reading hid before st overlay is written
    #pragma unroll
    for (int j=0;j<3;j++) {
      int col = (ntBase+j)*16 + ln15;
      float bb = b2[col];
      #pragma unroll
      for (int mt=0;mt<4;mt++)
        #pragma unroll
        for (int r=0;r<4;r++) {
          int row = mt*16 + quad*4 + r;
          st[row*196 + col] = acc[j][mt][r] + bb;
        }
    }
  }
  __syncthreads();
  // residual, coalesced, in-place
  for (int idx = tid; idx < 64*C_; idx += 256) {
    int r = idx / C_, c = idx % C_;
    size_t gr = (size_t)(r0 + r)*C_ + c;
    y[gr] = y[gr] + st[r*196 + c];
  }
}

extern "C" void kernel_launch(void* const* d_in, const int* in_sizes, int n_in,
                              void* d_out, int out_size, void* d_ws, size_t ws_size,
                              hipStream_t stream) {
  const float* x     = (const float*)d_in[0];
  const float* n1w   = (const float*)d_in[1];
  const float* n1b   = (const float*)d_in[2];
  const float* qkvw  = (const float*)d_in[3];
  const float* qkvb  = (const float*)d_in[4];
  const float* btab  = (const float*)d_in[5];
  const float* projw = (const float*)d_in[6];
  const float* projb = (const float*)d_in[7];
  const float* n2w   = (const float*)d_in[8];
  const float* n2b   = (const float*)d_in[9];
  const float* w1    = (const float*)d_in[10];
  const float* b1    = (const float*)d_in[11];
  const float* w2    = (const float*)d_in[12];
  const float* b2    = (const float*)d_in[13];
  const float* mask  = (const float*)d_in[14];
  const int*   rel   = (const int*)d_in[15];
  float* out = (float*)d_out;
  bfr*   wsp = (bfr*)d_ws;   // 884,736 B used

  k_prep<<<(WTOT+255)/256, 256, 0, stream>>>(qkvw, projw, w1, w2, wsp);
  k_attn<<<NWIN, 256, 0, stream>>>(x, n1w, n1b, wsp, qkvb, btab, rel, mask, projb, out);
  k_mlp<<<ROWS/64, 256, 0, stream>>>(out, n2w, n2b, wsp, b1, b2);
}

// Round 7
// 662.948 us; speedup vs baseline: 4.4135x; 1.3609x over previous
//
#include <hip/hip_runtime.h>
#include <math.h>

#define B_    32
#define HH    56
#define WW_   56
#define C_    192
#define WS_   7
#define SHIFT_ 3
#define HEADS_ 6
#define DH    32
#define N_    49
#define NWIN  2048
#define ROWS  100352
#define HID_  768
#define QKVN  576

typedef __bf16 bfr;
typedef __bf16 bf8 __attribute__((ext_vector_type(8)));
typedef float  f32x4 __attribute__((ext_vector_type(4)));

#define MFMA16(a,b,c) __builtin_amdgcn_mfma_f32_16x16x32_bf16(a,b,c,0,0,0)

// ---- ws layout (bf16 elements) ----
#define OQW   0         // qkvwT [576][192]
#define OPW   110592    // projwT[192][192]
#define OW1   147456    // w1T   [768][192]
#define OW2   294912    // w2T   [192][768]
#define OBM   442368    // bmask [6][64][64][64]  (bias+mask, pads = -1e30)
#define WTOT  442368
#define BMTOT 1572864   // 6*64*64*64

// ================= k_prep: transpose + fp32->bf16 all weights =================
__global__ __launch_bounds__(256) void k_prep(
    const float* __restrict__ qkvw, const float* __restrict__ projw,
    const float* __restrict__ w1,   const float* __restrict__ w2,
    bfr* __restrict__ wsp)
{
  int idx = blockIdx.x*256 + threadIdx.x;
  if (idx >= WTOT) return;
  if (idx < OPW)      { int i=idx;      int n=i/192, k=i%192; wsp[idx] = (bfr)qkvw[k*QKVN + n]; }
  else if (idx < OW1) { int i=idx-OPW;  int n=i/192, k=i%192; wsp[idx] = (bfr)projw[k*C_ + n]; }
  else if (idx < OW2) { int i=idx-OW1;  int n=i/192, k=i%192; wsp[idx] = (bfr)w1[k*HID_ + n]; }
  else                { int i=idx-OW2;  int n=i/768, k=i%768; wsp[idx] = (bfr)w2[k*C_ + n]; }
}

// ================= k_prep2: bmask[head][wi][row64][col64] = bias + mask (pads -1e30) =========
__global__ __launch_bounds__(256) void k_prep2(
    const float* __restrict__ btab, const int* __restrict__ rel,
    const float* __restrict__ mask, bfr* __restrict__ bm)
{
  int idx = blockIdx.x*256 + threadIdx.x;   // [head][wi][row][col]
  if (idx >= BMTOT) return;
  int col = idx & 63, row = (idx>>6) & 63, wi = (idx>>12) & 63, head = idx>>18;
  float v = -1e30f;
  if (row < N_ && col < N_) {
    int e = row*N_ + col;
    v = btab[rel[e]*HEADS_ + head] + mask[(size_t)wi*N_*N_ + e];
  }
  bm[idx] = (bfr)v;
}

// ================= Kernel 1: LN1+shift+QKV+attn+proj+residual, head-pair streamed ============
// LDS (bytes):
#define SM_HS 0        // bfr hs[64][200]          25600  (LN'd input, persists)
#define SM_QS 25600    // bfr qs[2][64][36]         9216
#define SM_KS 34816    // bfr ks[2][64][36]         9216
#define SM_VT 44032    // bfr vT[2][32][72]         9216
#define SM_P  53248    // bfr P[64][72]             9216
#define SM_OV 62464    // bfr ov[64][36]            4608
#define SM_SR 67072    // int srows[64]              256
#define SM1_TOT 67328
#define HSP 200

__global__ __launch_bounds__(256) void k_attn(
    const float* __restrict__ x,
    const float* __restrict__ n1w, const float* __restrict__ n1b,
    const bfr*   __restrict__ wsp,
    const float* __restrict__ qkvb,
    const float* __restrict__ projb,
    float* __restrict__ out)
{
  __shared__ char smem[SM1_TOT];
  bfr*   hs    = (bfr*)(smem + SM_HS);
  bfr*   qs    = (bfr*)(smem + SM_QS);
  bfr*   ks    = (bfr*)(smem + SM_KS);
  bfr*   vT    = (bfr*)(smem + SM_VT);
  bfr*   P     = (bfr*)(smem + SM_P);
  bfr*   ov    = (bfr*)(smem + SM_OV);
  int*   srows = (int*)(smem + SM_SR);
  float* pj    = (float*)smem;   // overlay [64][196] fp32 = 50176 B over hs/qs/ks/vT

  const f32x4 ZERO4 = {0.f, 0.f, 0.f, 0.f};

  int win  = blockIdx.x;
  int tid  = threadIdx.x;
  int lane = tid & 63, wave = tid >> 6;
  int ln15 = lane & 15, quad = lane >> 4;
  int wi   = win & 63;

  // ---- srows + zero hs ----
  if (tid < N_) {
    int bb = win >> 6;
    int wh = wi >> 3, ww = wi & 7;
    int th = tid / WS_, tw = tid % WS_;
    int sh = wh*WS_ + th + SHIFT_; if (sh >= HH) sh -= HH;
    int sw = ww*WS_ + tw + SHIFT_; if (sw >= WW_) sw -= WW_;
    srows[tid] = bb*HH*WW_ + sh*WW_ + sw;
  }
  {
    int* hz = (int*)hs;
    for (int i = tid; i < 64*HSP/2; i += 256) hz[i] = 0;
  }
  __syncthreads();
  // ---- LN1 -> hs ----
  for (int r = wave; r < N_; r += 4) {
    const float* xr = x + (size_t)srows[r]*C_;
    float v0 = xr[lane], v1 = xr[lane+64], v2 = xr[lane+128];
    float s = v0+v1+v2, q = v0*v0+v1*v1+v2*v2;
    #pragma unroll
    for (int m = 32; m; m >>= 1) { s += __shfl_xor(s, m); q += __shfl_xor(q, m); }
    float mu = s*(1.f/C_), var = q*(1.f/C_) - mu*mu;
    float rs = rsqrtf(var + 1e-5f);
    hs[r*HSP + lane]     = (bfr)((v0-mu)*rs*n1w[lane]     + n1b[lane]);
    hs[r*HSP + lane+64]  = (bfr)((v1-mu)*rs*n1w[lane+64]  + n1b[lane+64]);
    hs[r*HSP + lane+128] = (bfr)((v2-mu)*rs*n1w[lane+128] + n1b[lane+128]);
  }
  __syncthreads();

  const bfr* qkvwT  = wsp + OQW;
  const bfr* projwT = wsp + OPW;
  const bfr* bmask  = wsp + OBM;

  f32x4 accp[3][4];   // proj accumulators, persist across heads
  #pragma unroll
  for (int j=0;j<3;j++)
    #pragma unroll
    for (int mt=0;mt<4;mt++) accp[j][mt] = ZERO4;

  for (int pair = 0; pair < 3; pair++) {
    // ---- QKV for this pair: wave handles col-tile (wave) of q(j=0),k(j=1),v(j=2) ----
    {
      f32x4 acc[3][4];
      #pragma unroll
      for (int j=0;j<3;j++)
        #pragma unroll
        for (int mt=0;mt<4;mt++) acc[j][mt] = ZERO4;
      for (int k0 = 0; k0 < C_; k0 += 32) {
        bf8 afr[4];
        #pragma unroll
        for (int mt=0;mt<4;mt++)
          afr[mt] = *(const bf8*)&hs[(mt*16+ln15)*HSP + k0 + quad*8];
        #pragma unroll
        for (int j=0;j<3;j++) {
          int colg = j*192 + pair*64 + wave*16 + ln15;
          bf8 bw = *(const bf8*)&qkvwT[(size_t)colg*192 + k0 + quad*8];
          #pragma unroll
          for (int mt=0;mt<4;mt++) acc[j][mt] = MFMA16(afr[mt], bw, acc[j][mt]);
        }
      }
      int colp = wave*16 + ln15;         // within-pair col 0..63
      int hl = colp >> 5, d = colp & 31;
      #pragma unroll
      for (int j=0;j<3;j++) {
        float bias = qkvb[j*192 + pair*64 + colp];
        #pragma unroll
        for (int mt=0;mt<4;mt++)
          #pragma unroll
          for (int r=0;r<4;r++) {
            int row = mt*16 + quad*4 + r;
            float vv = acc[j][mt][r] + bias;
            if (j == 0)      qs[(hl*64+row)*36 + d] = (bfr)(vv*0.17677669529663689f);
            else if (j == 1) ks[(hl*64+row)*36 + d] = (bfr)vv;
            else             vT[(hl*32+d)*72 + row] = (bfr)vv;
          }
      }
    }
    __syncthreads();

    for (int hl = 0; hl < 2; hl++) {
      int head = pair*2 + hl;
      // ---- QK^T: wave owns rows wave*16..+15, all 64 cols ----
      float val[4][4];   // [nt][r]
      {
        bf8 aq = *(const bf8*)&qs[(hl*64 + wave*16 + ln15)*36 + quad*8];
        #pragma unroll
        for (int nt = 0; nt < 4; nt++) {
          bf8 bk = *(const bf8*)&ks[(hl*64 + nt*16 + ln15)*36 + quad*8];
          f32x4 c = MFMA16(aq, bk, ZERO4);
          #pragma unroll
          for (int r=0;r<4;r++) val[nt][r] = c[r];
        }
      }
      // bias+mask (pads already -1e30 in table)
      {
        const bfr* bmh = bmask + (((size_t)head*64 + wi) << 12);
        #pragma unroll
        for (int nt=0;nt<4;nt++)
          #pragma unroll
          for (int r=0;r<4;r++)
            val[nt][r] += (float)bmh[(wave*16 + quad*4 + r)*64 + nt*16 + ln15];
      }
      // ---- register softmax over 64 cols (4 regs x 16 lanes) ----
      {
        float mx[4], sum[4];
        #pragma unroll
        for (int r=0;r<4;r++) {
          mx[r] = fmaxf(fmaxf(val[0][r], val[1][r]), fmaxf(val[2][r], val[3][r]));
          #pragma unroll
          for (int m = 1; m < 16; m <<= 1) mx[r] = fmaxf(mx[r], __shfl_xor(mx[r], m));
        }
        #pragma unroll
        for (int nt=0;nt<4;nt++)
          #pragma unroll
          for (int r=0;r<4;r++) val[nt][r] = __expf(val[nt][r] - mx[r]);
        #pragma unroll
        for (int r=0;r<4;r++) {
          sum[r] = val[0][r] + val[1][r] + val[2][r] + val[3][r];
          #pragma unroll
          for (int m = 1; m < 16; m <<= 1) sum[r] += __shfl_xor(sum[r], m);
          sum[r] = 1.f / sum[r];
        }
        #pragma unroll
        for (int nt=0;nt<4;nt++)
          #pragma unroll
          for (int r=0;r<4;r++)
            P[(wave*16 + quad*4 + r)*72 + nt*16 + ln15] = (bfr)(val[nt][r]*sum[r]);
      }
      __syncthreads();
      // ---- PV: wave owns rows wave*16..+15, d-tiles nt=0..1 ----
      #pragma unroll
      for (int nt = 0; nt < 2; nt++) {
        f32x4 c = ZERO4;
        #pragma unroll
        for (int k0 = 0; k0 < 64; k0 += 32) {
          bf8 ap = *(const bf8*)&P[(wave*16 + ln15)*72 + k0 + quad*8];
          bf8 bv = *(const bf8*)&vT[(hl*32 + nt*16 + ln15)*72 + k0 + quad*8];
          c = MFMA16(ap, bv, c);
        }
        #pragma unroll
        for (int r=0;r<4;r++)
          ov[(wave*16 + quad*4 + r)*36 + nt*16 + ln15] = (bfr)c[r];
      }
      __syncthreads();
      // ---- proj K-step for this head (K=32 chunk at head*32) ----
      {
        bf8 afr[4];
        #pragma unroll
        for (int mt=0;mt<4;mt++)
          afr[mt] = *(const bf8*)&ov[(mt*16+ln15)*36 + quad*8];
        #pragma unroll
        for (int j=0;j<3;j++) {
          int col = (wave*3+j)*16 + ln15;
          bf8 bw = *(const bf8*)&projwT[(size_t)col*192 + head*32 + quad*8];
          #pragma unroll
          for (int mt=0;mt<4;mt++) accp[j][mt] = MFMA16(afr[mt], bw, accp[j][mt]);
        }
      }
    }
  }

  // ---- epilogue: bias -> pj overlay -> coalesced residual+scatter ----
  #pragma unroll
  for (int j=0;j<3;j++) {
    int col = (wave*3+j)*16 + ln15;
    float pb = projb[col];
    #pragma unroll
    for (int mt=0;mt<4;mt++)
      #pragma unroll
      for (int r=0;r<4;r++)
        pj[(mt*16 + quad*4 + r)*196 + col] = accp[j][mt][r] + pb;
  }
  __syncthreads();
  for (int idx = tid; idx < N_*C_; idx += 256) {
    int n = idx / C_, c = idx % C_;
    size_t gr = (size_t)srows[n]*C_ + c;
    out[gr] = x[gr] + pj[n*196 + c];
  }
}

// ================= Kernel 2: LN2 + fc1 + GELU + fc2 + residual, 32 rows/block ================
#define SM2_TS  0        // bfr ts[32][200]   12800
#define SM2_HID 12800    // bfr hid[32][776]  49664 ; overlay: float st[32][196] 25088
#define SM2_TOT 62464

__global__ __launch_bounds__(256) void k_mlp(
    float* __restrict__ y,
    const float* __restrict__ n2w, const float* __restrict__ n2b,
    const bfr* __restrict__ wsp,
    const float* __restrict__ b1, const float* __restrict__ b2)
{
  __shared__ char smem[SM2_TOT];
  bfr*   ts  = (bfr*)(smem + SM2_TS);
  bfr*   hid = (bfr*)(smem + SM2_HID);
  float* st  = (float*)(smem + SM2_HID);

  const f32x4 ZERO4 = {0.f, 0.f, 0.f, 0.f};

  int r0 = blockIdx.x * 32;
  int tid = threadIdx.x;
  int lane = tid & 63, wave = tid >> 6;
  int ln15 = lane & 15, quad = lane >> 4;

  // ---- LN2 ----
  for (int r = wave; r < 32; r += 4) {
    const float* yr = y + (size_t)(r0 + r)*C_;
    float v0 = yr[lane], v1 = yr[lane+64], v2 = yr[lane+128];
    float s = v0+v1+v2, q = v0*v0+v1*v1+v2*v2;
    #pragma unroll
    for (int m = 32; m; m >>= 1) { s += __shfl_xor(s, m); q += __shfl_xor(q, m); }
    float mu = s*(1.f/C_), var = q*(1.f/C_) - mu*mu;
    float rs = rsqrtf(var + 1e-5f);
    ts[r*HSP + lane]     = (bfr)((v0-mu)*rs*n2w[lane]     + n2b[lane]);
    ts[r*HSP + lane+64]  = (bfr)((v1-mu)*rs*n2w[lane+64]  + n2b[lane+64]);
    ts[r*HSP + lane+128] = (bfr)((v2-mu)*rs*n2w[lane+128] + n2b[lane+128]);
  }
  __syncthreads();

  // ---- fc1 + exact GELU (M=32, N=768, K=192) ----
  {
    const bfr* w1T = wsp + OW1;
    for (int ch = 0; ch < 4; ch++) {
      f32x4 acc[3][2];
      #pragma unroll
      for (int j=0;j<3;j++)
        #pragma unroll
        for (int mt=0;mt<2;mt++) acc[j][mt] = ZERO4;
      for (int k0 = 0; k0 < C_; k0 += 32) {
        bf8 afr[2];
        #pragma unroll
        for (int mt=0;mt<2;mt++)
          afr[mt] = *(const bf8*)&ts[(mt*16+ln15)*HSP + k0 + quad*8];
        #pragma unroll
        for (int j=0;j<3;j++) {
          int col = (wave*12 + ch*3 + j)*16 + ln15;
          bf8 bw = *(const bf8*)&w1T[(size_t)col*192 + k0 + quad*8];
          #pragma unroll
          for (int mt=0;mt<2;mt++) acc[j][mt] = MFMA16(afr[mt], bw, acc[j][mt]);
        }
      }
      #pragma unroll
      for (int j=0;j<3;j++) {
        int col = (wave*12 + ch*3 + j)*16 + ln15;
        float bb = b1[col];
        #pragma unroll
        for (int mt=0;mt<2;mt++)
          #pragma unroll
          for (int r=0;r<4;r++) {
            int row = mt*16 + quad*4 + r;
            float g = acc[j][mt][r] + bb;
            hid[row*776 + col] = (bfr)(0.5f*g*(1.f + erff(g*0.70710678118654752f)));
          }
      }
    }
  }
  __syncthreads();

  // ---- fc2 (M=32, N=192, K=768) ----
  {
    const bfr* w2T = wsp + OW2;
    f32x4 acc[3][2];
    #pragma unroll
    for (int j=0;j<3;j++)
      #pragma unroll
      for (int mt=0;mt<2;mt++) acc[j][mt] = ZERO4;
    for (int k0 = 0; k0 < HID_; k0 += 32) {
      bf8 afr[2];
      #pragma unroll
      for (int mt=0;mt<2;mt++)
        afr[mt] = *(const bf8*)&hid[(mt*16+ln15)*776 + k0 + quad*8];
      #pragma unroll
      for (int j=0;j<3;j++) {
        int col = (wave*3+j)*16 + ln15;
        bf8 bw = *(const bf8*)&w2T[(size_t)col*768 + k0 + quad*8];
        #pragma unroll
        for (int mt=0;mt<2;mt++) acc[j][mt] = MFMA16(afr[mt], bw, acc[j][mt]);
      }
    }
    __syncthreads();   // hid reads done before st overlay write
    #pragma unroll
    for (int j=0;j<3;j++) {
      int col = (wave*3+j)*16 + ln15;
      float bb = b2[col];
      #pragma unroll
      for (int mt=0;mt<2;mt++)
        #pragma unroll
        for (int r=0;r<4;r++) {
          int row = mt*16 + quad*4 + r;
          st[row*196 + col] = acc[j][mt][r] + bb;
        }
    }
  }
  __syncthreads();
  // residual, coalesced, in-place
  for (int idx = tid; idx < 32*C_; idx += 256) {
    int r = idx / C_, c = idx % C_;
    size_t gr = (size_t)(r0 + r)*C_ + c;
    y[gr] = y[gr] + st[r*196 + c];
  }
}

extern "C" void kernel_launch(void* const* d_in, const int* in_sizes, int n_in,
                              void* d_out, int out_size, void* d_ws, size_t ws_size,
                              hipStream_t stream) {
  const float* x     = (const float*)d_in[0];
  const float* n1w   = (const float*)d_in[1];
  const float* n1b   = (const float*)d_in[2];
  const float* qkvw  = (const float*)d_in[3];
  const float* qkvb  = (const float*)d_in[4];
  const float* btab  = (const float*)d_in[5];
  const float* projw = (const float*)d_in[6];
  const float* projb = (const float*)d_in[7];
  const float* n2w   = (const float*)d_in[8];
  const float* n2b   = (const float*)d_in[9];
  const float* w1    = (const float*)d_in[10];
  const float* b1    = (const float*)d_in[11];
  const float* w2    = (const float*)d_in[12];
  const float* b2    = (const float*)d_in[13];
  const float* mask  = (const float*)d_in[14];
  const int*   rel   = (const int*)d_in[15];
  float* out = (float*)d_out;
  bfr*   wsp = (bfr*)d_ws;   // (442368 + 1572864) * 2 B ~= 4.03 MB

  k_prep<<<(WTOT+255)/256, 256, 0, stream>>>(qkvw, projw, w1, w2, wsp);
  k_prep2<<<(BMTOT+255)/256, 256, 0, stream>>>(btab, rel, mask, wsp + OBM);
  k_attn<<<NWIN, 256, 0, stream>>>(x, n1w, n1b, wsp, qkvb, projb, out);
  k_mlp<<<ROWS/32, 256, 0, stream>>>(out, n2w, n2b, wsp, b1, b2);
}